// Round 3
// baseline (33680.762 us; speedup 1.0000x reference)
//
#include <hip/hip_runtime.h>
#include <hip/hip_bf16.h>
#include <math.h>

// Problem constants
constexpr int B_  = 64;
constexpr int T_  = 120;
constexpr int TITLE_ = 20;
constexpr int H_  = 768;
constexpr int L_  = 12;
constexpr int NH_ = 12;
constexpr int DH_ = 64;
constexpr int FF_ = 3072;
constexpr int V_  = 21128;
constexpr int M_  = B_ * T_;      // 7680 tokens
constexpr int VC_ = 2048;         // classifier V-chunk width

// ---------------- block reductions (any blockDim multiple of 64, <=512) ----
__device__ __forceinline__ float block_reduce_sum(float v) {
  __shared__ float red[8];
  #pragma unroll
  for (int o = 32; o > 0; o >>= 1) v += __shfl_down(v, o, 64);
  int lane = threadIdx.x & 63, w = threadIdx.x >> 6;
  __syncthreads();
  if (lane == 0) red[w] = v;
  __syncthreads();
  float total = 0.0f;
  int nw = (blockDim.x + 63) >> 6;
  for (int i = 0; i < nw; i++) total += red[i];
  return total;
}

__device__ __forceinline__ float block_reduce_max(float v) {
  __shared__ float red[8];
  #pragma unroll
  for (int o = 32; o > 0; o >>= 1) v = fmaxf(v, __shfl_down(v, o, 64));
  int lane = threadIdx.x & 63, w = threadIdx.x >> 6;
  __syncthreads();
  if (lane == 0) red[w] = v;
  __syncthreads();
  float total = -1e30f;
  int nw = (blockDim.x + 63) >> 6;
  for (int i = 0; i < nw; i++) total = fmaxf(total, red[i]);
  return total;
}

// ---------------- embedding + LN --------------------------------------------
// grid = M_ blocks, block = 256 (each thread owns 3 of 768 channels)
__global__ __launch_bounds__(256) void embed_ln_kernel(
    const int* __restrict__ x, const float* __restrict__ we,
    const float* __restrict__ pe, const float* __restrict__ te,
    const float* __restrict__ g, const float* __restrict__ b,
    float* __restrict__ h) {
  int tok = blockIdx.x;
  int t = tok % T_;
  int wid = x[tok];
  int tid = threadIdx.x;
  float vals[3];
  float lsum = 0.0f;
  #pragma unroll
  for (int i = 0; i < 3; i++) {
    int c = tid + i * 256;
    float v = we[wid * H_ + c] + pe[t * H_ + c] + te[c];
    vals[i] = v; lsum += v;
  }
  float mean = block_reduce_sum(lsum) * (1.0f / H_);
  float lvar = 0.0f;
  #pragma unroll
  for (int i = 0; i < 3; i++) { float d = vals[i] - mean; lvar += d * d; }
  float var = block_reduce_sum(lvar) * (1.0f / H_);
  float rstd = rsqrtf(var + 1e-12f);
  #pragma unroll
  for (int i = 0; i < 3; i++) {
    int c = tid + i * 256;
    h[tok * H_ + c] = (vals[i] - mean) * rstd * g[c] + b[c];
  }
}

// ---------------- residual + LN (in place on h) ------------------------------
__global__ __launch_bounds__(256) void resid_ln_kernel(
    float* __restrict__ h, const float* __restrict__ delta,
    const float* __restrict__ g, const float* __restrict__ b) {
  int tok = blockIdx.x;
  int tid = threadIdx.x;
  float vals[3];
  float lsum = 0.0f;
  #pragma unroll
  for (int i = 0; i < 3; i++) {
    int c = tid + i * 256;
    float v = h[tok * H_ + c] + delta[tok * H_ + c];
    vals[i] = v; lsum += v;
  }
  float mean = block_reduce_sum(lsum) * (1.0f / H_);
  float lvar = 0.0f;
  #pragma unroll
  for (int i = 0; i < 3; i++) { float d = vals[i] - mean; lvar += d * d; }
  float var = block_reduce_sum(lvar) * (1.0f / H_);
  float rstd = rsqrtf(var + 1e-12f);
  #pragma unroll
  for (int i = 0; i < 3; i++) {
    int c = tid + i * 256;
    h[tok * H_ + c] = (vals[i] - mean) * rstd * g[c] + b[c];
  }
}

// ---------------- generic tiled GEMM: C[M,N] = A[M,K](f32) @ W[K,N](f32) + bias
// ACT: 0 = none, 1 = exact gelu.  ldw = row stride of W (for V-chunked Wc).
// M must be a multiple of 64; K a multiple of 16; N arbitrary (guarded).
template <int ACT>
__global__ __launch_bounds__(256) void gemm_bias_act(
    const float* __restrict__ A, const float* __restrict__ W,
    const float* __restrict__ bias, float* __restrict__ C,
    int M, int N, int K, int ldw) {
  constexpr int BM = 64, BN = 64, BK = 16;
  __shared__ float As[BK][BM + 4];  // +4 keeps rows 16B-aligned, breaks conflicts
  __shared__ float Ws[BK][BN];
  const int tid = threadIdx.x;
  const int tx = tid & 15, ty = tid >> 4;
  const int m0 = blockIdx.y * BM, n0 = blockIdx.x * BN;
  float acc[4][4] = {};
  for (int k0 = 0; k0 < K; k0 += BK) {
    #pragma unroll
    for (int i = 0; i < 4; i++) {
      int idx = tid + i * 256;          // 0..1023 over 64x16 A tile
      int r = idx >> 4, c = idx & 15;
      As[c][r] = A[(m0 + r) * K + k0 + c];
    }
    #pragma unroll
    for (int i = 0; i < 4; i++) {
      int idx = tid + i * 256;          // 0..1023 over 16x64 W tile
      int r = idx >> 6, c = idx & 63;
      int n = n0 + c;
      Ws[r][c] = (n < N) ? W[(k0 + r) * ldw + n] : 0.0f;
    }
    __syncthreads();
    #pragma unroll
    for (int kk = 0; kk < BK; kk++) {
      float4 av = *reinterpret_cast<const float4*>(&As[kk][ty * 4]);
      float4 wv = *reinterpret_cast<const float4*>(&Ws[kk][tx * 4]);
      float a[4] = {av.x, av.y, av.z, av.w};
      float w[4] = {wv.x, wv.y, wv.z, wv.w};
      #pragma unroll
      for (int i = 0; i < 4; i++)
        #pragma unroll
        for (int j = 0; j < 4; j++)
          acc[i][j] += a[i] * w[j];
    }
    __syncthreads();
  }
  #pragma unroll
  for (int i = 0; i < 4; i++) {
    int m = m0 + ty * 4 + i;
    #pragma unroll
    for (int j = 0; j < 4; j++) {
      int n = n0 + tx * 4 + j;
      if (n < N) {
        float v = acc[i][j] + bias[n];
        if (ACT == 1) v = 0.5f * v * (1.0f + erff(v * 0.70710678118654752f));
        C[m * N + n] = v;
      }
    }
  }
}

// ---------------- fused attention: one block per (b, head, q-row) ------------
// q,k,v are f32 [M_,H_] with head layout col = hh*DH + d; ctx same layout.
__global__ __launch_bounds__(128) void attn_fused_kernel(
    const float* __restrict__ qb, const float* __restrict__ kb,
    const float* __restrict__ vb, float* __restrict__ ctx) {
  int bid = blockIdx.x;                // b*NH*T + hh*T + qt
  int qt = bid % T_;
  int rem = bid / T_;
  int hh = rem % NH_;
  int b = rem / NH_;
  int tid = threadIdx.x;
  __shared__ float qrow[DH_];
  __shared__ float sc[T_];

  const float* qptr = qb + ((size_t)(b * T_ + qt) * H_ + hh * DH_);
  if (tid < DH_) qrow[tid] = qptr[tid];
  __syncthreads();

  float sval = -1e30f;
  if (tid < T_) {
    const float* kptr = kb + ((size_t)(b * T_ + tid) * H_ + hh * DH_);
    float s = 0.0f;
    #pragma unroll 8
    for (int d = 0; d < DH_; d++) s += qrow[d] * kptr[d];
    s *= 0.125f;  // 1/sqrt(64)
    // UniLM mask: key<TITLE always visible; content keys visible causally to content rows
    bool allowed = (tid < TITLE_) || (qt >= TITLE_ && tid <= qt);
    if (!allowed) s -= 10000.0f;
    sc[tid] = s;
    sval = s;
  }
  float mx = block_reduce_max(sval);
  float ex = 0.0f;
  if (tid < T_) { ex = expf(sc[tid] - mx); sc[tid] = ex; }
  float denom = block_reduce_sum(ex);
  float inv = 1.0f / denom;
  if (tid < DH_) {
    float acc = 0.0f;
    const float* vcol = vb + ((size_t)b * T_ * H_ + hh * DH_ + tid);
    for (int t = 0; t < T_; t++) acc += sc[t] * vcol[(size_t)t * H_];
    ctx[(size_t)(b * T_ + qt) * H_ + hh * DH_ + tid] = acc * inv;
  }
}

// ---------------- online-softmax loss over V chunks ---------------------------
__global__ void loss_init_kernel(float* marr, float* sarr, float* ylg) {
  int i = blockIdx.x * 256 + threadIdx.x;
  if (i < M_) { marr[i] = -1e30f; sarr[i] = 0.0f; ylg[i] = 0.0f; }
}

// one block (256 threads) per token; logits row stride = vc
__global__ __launch_bounds__(256) void loss_update_kernel(
    const float* __restrict__ logits, const int* __restrict__ y,
    float* __restrict__ marr, float* __restrict__ sarr, float* __restrict__ ylg,
    int c0, int vc) {
  int tok = blockIdx.x;
  int tid = threadIdx.x;
  const float* row = logits + (size_t)tok * vc;
  float lmax = -1e30f;
  for (int i = tid; i < vc; i += 256) lmax = fmaxf(lmax, row[i]);
  float cmax = block_reduce_max(lmax);
  float mold = marr[tok];           // all threads read before tid0's write below
  float sold = sarr[tok];
  float mnew = fmaxf(mold, cmax);
  float lsum = 0.0f;
  for (int i = tid; i < vc; i += 256) lsum += expf(row[i] - mnew);
  float csum = block_reduce_sum(lsum);   // contains __syncthreads -> safe to write after
  if (tid == 0) {
    marr[tok] = mnew;
    sarr[tok] = sold * expf(mold - mnew) + csum;
    int yt = y[tok];
    if (yt >= c0 && yt < c0 + vc) ylg[tok] = row[yt - c0];
  }
}

// Reference OUTPUT dtype is float32 (jnp.mean of f32) -> d_out is float*.
__global__ __launch_bounds__(256) void loss_final_kernel(
    const float* __restrict__ marr, const float* __restrict__ sarr,
    const float* __restrict__ ylg, float* __restrict__ out) {
  int tid = threadIdx.x;
  float lsum = 0.0f;
  for (int i = tid; i < M_; i += 256)
    lsum += (marr[i] + logf(sarr[i])) - ylg[i];
  float total = block_reduce_sum(lsum);
  if (tid == 0) out[0] = total / (float)M_;
}

// ---------------- host orchestration -----------------------------------------
extern "C" void kernel_launch(void* const* d_in, const int* in_sizes, int n_in,
                              void* d_out, int out_size, void* d_ws, size_t ws_size,
                              hipStream_t stream) {
  const int*   x        = (const int*)d_in[0];
  const int*   y        = (const int*)d_in[1];
  const float* word_emb = (const float*)d_in[2];
  const float* pos_emb  = (const float*)d_in[3];
  const float* type_emb = (const float*)d_in[4];
  const float* emb_ln_g = (const float*)d_in[5];
  const float* emb_ln_b = (const float*)d_in[6];
  const float* Wq = (const float*)d_in[7];
  const float* Wk = (const float*)d_in[8];
  const float* Wv = (const float*)d_in[9];
  const float* Wo = (const float*)d_in[10];
  const float* W1 = (const float*)d_in[11];
  const float* W2 = (const float*)d_in[12];
  const float* bq = (const float*)d_in[13];
  const float* bk = (const float*)d_in[14];
  const float* bv = (const float*)d_in[15];
  const float* bo = (const float*)d_in[16];
  const float* b1 = (const float*)d_in[17];
  const float* b2 = (const float*)d_in[18];
  const float* ln1_g = (const float*)d_in[19];
  const float* ln1_b = (const float*)d_in[20];
  const float* ln2_g = (const float*)d_in[21];
  const float* ln2_b = (const float*)d_in[22];
  const float* Wc = (const float*)d_in[23];
  const float* bc = (const float*)d_in[24];

  // workspace layout (floats):
  //   h    [M_*H_]            @ 0          (5,898,240)
  //   tmp  [M_*FF_]           @ 5,898,240  (23,592,960)  also q/k/v, logits chunk
  //   buf2 [M_*H_]            @ 29,491,200 (5,898,240)
  //   marr/sarr/ylg [M_] each @ 35,389,440
  // total = 35,412,480 floats = ~142 MB
  float* ws   = (float*)d_ws;
  float* h    = ws;
  float* tmp  = ws + 5898240;
  float* buf2 = ws + 29491200;
  float* marr = ws + 35389440;
  float* sarr = marr + M_;
  float* ylg  = sarr + M_;

  float* q = tmp;
  float* k = tmp + (size_t)M_ * H_;
  float* v = tmp + (size_t)2 * M_ * H_;

  dim3 blk256(256);
  dim3 gH((H_ + 63) / 64, M_ / 64);    // 12 x 120
  dim3 gFF((FF_ + 63) / 64, M_ / 64);  // 48 x 120

  embed_ln_kernel<<<M_, blk256, 0, stream>>>(x, word_emb, pos_emb, type_emb,
                                             emb_ln_g, emb_ln_b, h);

  for (int l = 0; l < L_; l++) {
    const float* Wq_l = Wq + (size_t)l * H_ * H_;
    const float* Wk_l = Wk + (size_t)l * H_ * H_;
    const float* Wv_l = Wv + (size_t)l * H_ * H_;
    const float* Wo_l = Wo + (size_t)l * H_ * H_;
    const float* W1_l = W1 + (size_t)l * H_ * FF_;
    const float* W2_l = W2 + (size_t)l * FF_ * H_;

    gemm_bias_act<0><<<gH, blk256, 0, stream>>>(h, Wq_l, bq + l * H_, q, M_, H_, H_, H_);
    gemm_bias_act<0><<<gH, blk256, 0, stream>>>(h, Wk_l, bk + l * H_, k, M_, H_, H_, H_);
    gemm_bias_act<0><<<gH, blk256, 0, stream>>>(h, Wv_l, bv + l * H_, v, M_, H_, H_, H_);

    attn_fused_kernel<<<B_ * NH_ * T_, 128, 0, stream>>>(q, k, v, buf2);

    gemm_bias_act<0><<<gH, blk256, 0, stream>>>(buf2, Wo_l, bo + l * H_, tmp, M_, H_, H_, H_);
    resid_ln_kernel<<<M_, blk256, 0, stream>>>(h, tmp, ln1_g + l * H_, ln1_b + l * H_);

    gemm_bias_act<1><<<gFF, blk256, 0, stream>>>(h, W1_l, b1 + l * FF_, tmp, M_, FF_, H_, FF_);
    gemm_bias_act<0><<<gH, blk256, 0, stream>>>(tmp, W2_l, b2 + l * H_, buf2, M_, H_, FF_, H_);
    resid_ln_kernel<<<M_, blk256, 0, stream>>>(h, buf2, ln2_g + l * H_, ln2_b + l * H_);
  }

  // classifier + online-softmax NLL, chunked over V
  loss_init_kernel<<<(M_ + 255) / 256, blk256, 0, stream>>>(marr, sarr, ylg);
  for (int c0 = 0; c0 < V_; c0 += VC_) {
    int vc = (V_ - c0) < VC_ ? (V_ - c0) : VC_;
    dim3 gC((vc + 63) / 64, M_ / 64);
    gemm_bias_act<0><<<gC, blk256, 0, stream>>>(h, Wc + c0, bc + c0, tmp, M_, vc, H_, V_);
    loss_update_kernel<<<M_, blk256, 0, stream>>>(tmp, y, marr, sarr, ylg, c0, vc);
  }
  loss_final_kernel<<<1, blk256, 0, stream>>>(marr, sarr, ylg, (float*)d_out);
}